// Round 11
// baseline (100.621 us; speedup 1.0000x reference)
//
#include <hip/hip_runtime.h>
#include <hip/hip_bf16.h>

// Deformable conv2d (v1, align_corners=True, zeros padding), NHWC-bf16 + MFMA.
// R11 = R10 (XOR-swizzled LDS tile) with the kn loop restructured for I$ and
// cross-iteration pipelining:
//  - #pragma unroll 3 (body ~6KB, I$-resident; R2-R10 fast variants unrolled
//    9x into ~25KB vs 32KB L1I)
//  - offsets staged one iteration ahead as loop-carried scalars (no register
//    arrays -> no forced full unroll, no scratch)
//  - factorized bilinear: cy*(ax*q00+bx*q01)+dy*(ax*q10+bx*q11)  (exact)
//  - ds_reads + A-loads issued at iteration top; latency hides under interp
// x(4,64,128,128) f32, offset(4,18,128,128) f32, weight(64,64,9) f32
// -> out(4,64,128,128) f32.  iy = oh + off_y, ix = ow + off_x.

#define NB 4
#define CI 64
#define HH 128
#define WW 128
#define OCH 64
#define KNN 9
#define HW (HH * WW)

typedef unsigned int u32;
typedef unsigned short u16;
typedef __attribute__((ext_vector_type(8))) short bf16x8;
typedef __attribute__((ext_vector_type(4))) float f32x4;

__device__ inline u16 f2bf(float f) {  // RNE
    u32 u = __float_as_uint(f);
    return (u16)((u + 0x7fffu + ((u >> 16) & 1u)) >> 16);
}
__device__ inline u32 pk2(float lo, float hi) {
    return (u32)f2bf(lo) | ((u32)f2bf(hi) << 16);
}
__device__ inline float2 up2v(u32 u) {
    return float2{__uint_as_float(u << 16), __uint_as_float(u & 0xffff0000u)};
}
__device__ inline u32 pkrn(float2 s) {
    union { __hip_bfloat162 b; u32 u; } c;
    c.b = __float22bfloat162_rn(s);
    return c.u;
}

// ---- prologue: x NCHW f32 -> NHWC bf16, + weight -> A-fragment order bf16.
// wf layout: frag[kn][chunk(2)][strip(4)][lane(64)][j(8)]; lane holds
// A[m=lane&15][k=(lane>>4)*8+j], oc = strip*16+m, c = chunk*32+k.
__global__ __launch_bounds__(256) void prep_kernel(const float* __restrict__ x,
                                                   const float* __restrict__ w,
                                                   u16* __restrict__ xT,
                                                   u16* __restrict__ wf) {
    __shared__ float T[64 * 68];
    const int tid = threadIdx.x;
    if (blockIdx.x < NB * 256) {
        const int n = blockIdx.x >> 8;
        const int hw0 = (blockIdx.x & 255) << 6;
#pragma unroll
        for (int jj = 0; jj < 4; jj++) {
            int c = (tid >> 4) + (jj << 4);
            int hwq = (tid & 15) << 2;
            float4 v = *(const float4*)&x[(((n << 6) + c) << 14) + hw0 + hwq];
            *(float4*)&T[c * 68 + hwq] = v;
        }
        __syncthreads();
        const int hw_l = tid >> 2;
        const int cb = (tid & 3) << 4;
        u32 ou[8];
#pragma unroll
        for (int k = 0; k < 8; k++) {
            ou[k] = pk2(T[(cb + 2 * k) * 68 + hw_l], T[(cb + 2 * k + 1) * 68 + hw_l]);
        }
        u16* dst = xT + ((size_t)((n << 14) + hw0 + hw_l) << 6) + cb;
        *(uint4*)dst = make_uint4(ou[0], ou[1], ou[2], ou[3]);
        *(uint4*)(dst + 8) = make_uint4(ou[4], ou[5], ou[6], ou[7]);
    } else {
        int i = (blockIdx.x - NB * 256) * 256 + tid;
        if (i < KNN * 2 * 4 * 64 * 8) {
            int j = i & 7, l = (i >> 3) & 63, strip = (i >> 9) & 3,
                chunk = (i >> 11) & 1, kn = i >> 12;
            int oc = strip * 16 + (l & 15);
            int c = chunk * 32 + ((l >> 4) & 3) * 8 + j;
            wf[i] = f2bf(w[(oc * CI + c) * KNN + kn]);
        }
    }
}

// ---- main kernel: block = 8x8 patch (4 waves of 4x4), 64 oc, LDS input tile.
__global__ __launch_bounds__(256, 4) void dcn_main_kernel(const u16* __restrict__ xT,
                                                          const float* __restrict__ off,
                                                          const u16* __restrict__ wf,
                                                          float* __restrict__ out) {
    // 14x16 pixels x 64ch bf16; pixel row = 32 dw (128B); chunk q at q^(p&7).
    __shared__ __align__(16) u32 tile[224 * 32];  // 28,672 B
    const int tid = threadIdx.x;
    const int l = tid & 63;
    const int wv = tid >> 6;

    // XCD-affine decode: xcd = blockIdx&7; n = xcd>>1; half = xcd&1.
    const int b = blockIdx.x;
    const int xcd = b & 7;
    const int n = xcd >> 1;
    const int patch = (b >> 3) + ((xcd & 1) << 7);  // 0..255
    const int py = ((patch >> 4) << 3), px = ((patch & 15) << 3);
    const int ty = min(max(py - 3, 0), HH - 14);
    const int tx = min(max(px - 4, 0), WW - 16);

    const u16* xTn = xT + ((size_t)n << 20);
    const float* offn = off + n * (2 * KNN * HW);

    // cooperative tile load: threads 0..223 each move one pixel's 128 B,
    // chunk j (16B) lands at slot j^(p&7).
    if (tid < 224) {
        const int tr = tid >> 4, tc = tid & 15;
        const u16* src = xTn + ((((ty + tr) << 7) + (tx + tc)) << 6);
        u32* dst = &tile[tid << 5];
        const int sw = tid & 7;
#pragma unroll
        for (int j = 0; j < 8; j++) {
            *(uint4*)&dst[(j ^ sw) << 2] = *(const uint4*)(src + (j << 3));
        }
    }

    const int qy = ((wv >> 1) << 2), qx = ((wv & 1) << 2);
    const int col = l & 15;
    const int oh = py + qy + (col >> 2);
    const int ow = px + qx + (col & 3);
    const int rr = (oh << 7) + ow;
    const int qc = l >> 4;   // channel chunk index 0..3 (16B chunks)
    const int cb = qc << 3;  // channel base in halfwords

    const float* offp = offn + rr;
    // stage kn=0 offsets
    float soy = offp[0];
    float sox = offp[HW];

    __syncthreads();  // tile resident

    const bf16x8* wfl = (const bf16x8*)wf + l;
    f32x4 acc[4] = {{0, 0, 0, 0}, {0, 0, 0, 0}, {0, 0, 0, 0}, {0, 0, 0, 0}};

#pragma unroll 3
    for (int kn = 0; kn < KNN; kn++) {
        // consume staged offsets
        float iy = (float)oh + soy, ix = (float)ow + sox;
        float y0f = floorf(iy), x0f = floorf(ix);
        float wy1 = iy - y0f, wy0 = 1.f - wy1;
        float wx1 = ix - x0f, wx0 = 1.f - wx1;
        float my0 = (y0f >= 0.f && y0f <= 127.f) ? 1.f : 0.f;
        float my1 = (y0f >= -1.f && y0f <= 126.f) ? 1.f : 0.f;
        float mx0 = (x0f >= 0.f && x0f <= 127.f) ? 1.f : 0.f;
        float mx1 = (x0f >= -1.f && x0f <= 126.f) ? 1.f : 0.f;
        float ax = wx0 * mx0, bx = wx1 * mx1;   // x-factors (masks folded)
        float cy = wy0 * my0, dy = wy1 * my1;   // y-factors
        int y0 = min(max((int)y0f, 0), 127), y1 = min(max((int)y0f + 1, 0), 127);
        int x0 = min(max((int)x0f, 0), 127), x1 = min(max((int)x0f + 1, 0), 127);

        const int dy0 = min(max(y0 - ty, 0), 13), dy1 = min(max(y1 - ty, 0), 13);
        const int dx0 = min(max(x0 - tx, 0), 15), dx1 = min(max(x1 - tx, 0), 15);
        const int P0 = (dy0 << 4) + dx0, P1 = (dy0 << 4) + dx1;
        const int P2 = (dy1 << 4) + dx0, P3 = (dy1 << 4) + dx1;
        const bool oot = (y0 < ty) | (y1 > ty + 13) | (x0 < tx) | (x1 > tx + 15);

        // issue all 8 ds_read_b128 up front (latency hides under addr/interp)
        uint4 C0 = *(const uint4*)&tile[(P0 << 5) + (((qc    ) ^ (P0 & 7)) << 2)];
        uint4 C1 = *(const uint4*)&tile[(P1 << 5) + (((qc    ) ^ (P1 & 7)) << 2)];
        uint4 C2 = *(const uint4*)&tile[(P2 << 5) + (((qc    ) ^ (P2 & 7)) << 2)];
        uint4 C3 = *(const uint4*)&tile[(P3 << 5) + (((qc    ) ^ (P3 & 7)) << 2)];
        uint4 D0 = *(const uint4*)&tile[(P0 << 5) + (((qc + 4) ^ (P0 & 7)) << 2)];
        uint4 D1 = *(const uint4*)&tile[(P1 << 5) + (((qc + 4) ^ (P1 & 7)) << 2)];
        uint4 D2 = *(const uint4*)&tile[(P2 << 5) + (((qc + 4) ^ (P2 & 7)) << 2)];
        uint4 D3 = *(const uint4*)&tile[(P3 << 5) + (((qc + 4) ^ (P3 & 7)) << 2)];

        // stage kn+1 offsets (issued now -> ~full iteration of flight)
        {
            const int knx = min(kn + 1, KNN - 1);
            soy = offp[(size_t)(2 * knx) * HW];
            sox = offp[(size_t)(2 * knx + 1) * HW];
        }

        if (oot) {  // rare: exact global gather fallback
            const int O0 = ((y0 << 7) + x0) << 6, O1 = ((y0 << 7) + x1) << 6;
            const int O2 = ((y1 << 7) + x0) << 6, O3 = ((y1 << 7) + x1) << 6;
            C0 = *(const uint4*)(xTn + O0 + cb);
            C1 = *(const uint4*)(xTn + O1 + cb);
            C2 = *(const uint4*)(xTn + O2 + cb);
            C3 = *(const uint4*)(xTn + O3 + cb);
            D0 = *(const uint4*)(xTn + O0 + cb + 32);
            D1 = *(const uint4*)(xTn + O1 + cb + 32);
            D2 = *(const uint4*)(xTn + O2 + cb + 32);
            D3 = *(const uint4*)(xTn + O3 + cb + 32);
        }

        const bf16x8* wk = wfl + (kn << 3) * 64;
#pragma unroll
        for (int cc = 0; cc < 2; cc++) {
            const u32* q0 = (const u32*)(cc ? &D0 : &C0);
            const u32* q1 = (const u32*)(cc ? &D1 : &C1);
            const u32* q2 = (const u32*)(cc ? &D2 : &C2);
            const u32* q3 = (const u32*)(cc ? &D3 : &C3);
            union { u32 u[4]; bf16x8 v; } B;
#pragma unroll
            for (int k = 0; k < 4; k++) {
                float2 e0 = up2v(q0[k]), e1 = up2v(q1[k]);
                float2 e2 = up2v(q2[k]), e3 = up2v(q3[k]);
                float2 h0, h1, s;
                h0.x = fmaf(e1.x, bx, e0.x * ax);
                h0.y = fmaf(e1.y, bx, e0.y * ax);
                h1.x = fmaf(e3.x, bx, e2.x * ax);
                h1.y = fmaf(e3.y, bx, e2.y * ax);
                s.x = fmaf(h1.x, dy, h0.x * cy);
                s.y = fmaf(h1.y, dy, h0.y * cy);
                B.u[k] = pkrn(s);
            }
#pragma unroll
            for (int s4 = 0; s4 < 4; s4++) {
                bf16x8 A = wk[((cc << 2) + s4) * 64];
                acc[s4] = __builtin_amdgcn_mfma_f32_16x16x32_bf16(A, B.v, acc[s4], 0, 0, 0);
            }
        }
    }

    // epilogue: D layout col(pixel)=l&15, row(oc-in-strip)=(l>>4)*4+reg
    const int rq = l >> 4;
    float* op = out + ((size_t)(n * OCH) << 14);
#pragma unroll
    for (int s = 0; s < 4; s++) {
        const int ocb = (s << 4) + (rq << 2);
#pragma unroll
        for (int g = 0; g < 4; g++) {
            op[((ocb + g) << 14) + rr] = acc[s][g];
        }
    }
}

// ---- fallback (ws too small): round-1 style direct kernel
__global__ __launch_bounds__(256) void dcn_fallback_kernel(
    const float* __restrict__ x, const float* __restrict__ off,
    const float* __restrict__ w, float* __restrict__ out) {
    int p = blockIdx.x * blockDim.x + threadIdx.x;
    int n = p / HW, r = p % HW, oh = r / WW, ow = r % WW;
    float acc[OCH];
#pragma unroll
    for (int i = 0; i < OCH; i++) acc[i] = 0.f;
    const float* xn = x + n * (CI * HW);
    const float* offn = off + n * (2 * KNN * HW);
    for (int kn = 0; kn < KNN; kn++) {
        float iy = (float)oh + offn[(2 * kn) * HW + r];
        float ix = (float)ow + offn[(2 * kn + 1) * HW + r];
        float y0f = floorf(iy), x0f = floorf(ix);
        float wy1 = iy - y0f, wy0 = 1.f - wy1, wx1 = ix - x0f, wx0 = 1.f - wx1;
        float my0 = (y0f >= 0.f && y0f <= 127.f) ? 1.f : 0.f;
        float my1 = (y0f >= -1.f && y0f <= 126.f) ? 1.f : 0.f;
        float mx0 = (x0f >= 0.f && x0f <= 127.f) ? 1.f : 0.f;
        float mx1 = (x0f >= -1.f && x0f <= 126.f) ? 1.f : 0.f;
        float w00 = wy0 * wx0 * my0 * mx0, w01 = wy0 * wx1 * my0 * mx1;
        float w10 = wy1 * wx0 * my1 * mx0, w11 = wy1 * wx1 * my1 * mx1;
        int y0 = min(max((int)y0f, 0), 127), y1 = min(max((int)y0f + 1, 0), 127);
        int x0 = min(max((int)x0f, 0), 127), x1 = min(max((int)x0f + 1, 0), 127);
        int o00 = y0 * WW + x0, o01 = y0 * WW + x1, o10 = y1 * WW + x0, o11 = y1 * WW + x1;
        for (int c = 0; c < CI; c++) {
            const float* xc = xn + c * HW;
            float s = xc[o00] * w00 + xc[o01] * w01 + xc[o10] * w10 + xc[o11] * w11;
#pragma unroll
            for (int oc = 0; oc < OCH; oc++) acc[oc] += w[(oc * CI + c) * KNN + kn] * s;
        }
    }
    float* outp = out + n * (OCH * HW) + r;
#pragma unroll
    for (int oc = 0; oc < OCH; oc++) outp[oc * HW] = acc[oc];
}

extern "C" void kernel_launch(void* const* d_in, const int* in_sizes, int n_in,
                              void* d_out, int out_size, void* d_ws, size_t ws_size,
                              hipStream_t stream) {
    const float* x = (const float*)d_in[0];
    const float* off = (const float*)d_in[1];
    const float* w = (const float*)d_in[2];
    float* out = (float*)d_out;

    const size_t xT_elems = (size_t)NB * HW * CI;             // 4,194,304 u16
    const size_t wf_elems = (size_t)KNN * 2 * 4 * 64 * 8;     // 36,864 u16
    const size_t need = (xT_elems + wf_elems) * sizeof(u16);  // ~8.46 MB

    if (ws_size >= need) {
        u16* xT = (u16*)d_ws;
        u16* wfr = xT + xT_elems;
        const int wf_blocks = (int)((wf_elems + 255) / 256);  // 144
        prep_kernel<<<NB * 256 + wf_blocks, 256, 0, stream>>>(x, w, xT, wfr);
        dcn_main_kernel<<<NB * 256, 256, 0, stream>>>(xT, off, wfr, out);
    } else {
        dcn_fallback_kernel<<<(NB * HW) / 256, 256, 0, stream>>>(x, off, w, out);
    }
}